// Round 7
// baseline (401.491 us; speedup 1.0000x reference)
//
#include <hip/hip_runtime.h>

typedef __attribute__((ext_vector_type(8))) short short8;
typedef __attribute__((ext_vector_type(4))) short short4v;
typedef __attribute__((ext_vector_type(4))) float float4v;
typedef unsigned short u16;

#define Sdim 256
#define Udim 128
#define Hdim 512
#define MT   32       // rows per block
#define XS   392      // xh stride (u16): 384+8
#define XLS  264      // xl stride (state cols only): 256+8
#define HS   520      // h stride: 512+8
#define NW   589824   // W1p+W2p+W3p elements
#define W1_OFF 0
#define W2_OFF 196608
#define W3_OFF 458752
#define G_OFF  589824  // G = W3@W1[0:256,:] packed frags (512x512 -> 262144 u16)
#define C3_OFF 851968  // u16 index of c3 (512 fp32 = 1024 u16-slots... cast to float*)
#define FLAG_BYTE 1705984
#define NSTEPS 21     // np-ref float32 h: floor(1/0.05f)=20 scaled + 1 unscaled

__device__ __forceinline__ float bf2f(u16 u) {
    union { unsigned int i; float f; } x; x.i = ((unsigned int)u) << 16; return x.f;
}
__device__ __forceinline__ u16 f2bf(float f) {
    union { float f; unsigned int i; } x; x.f = f;
    unsigned int r = x.i + 0x7FFFu + ((x.i >> 16) & 1u);  // RNE
    return (u16)(r >> 16);
}

// bf16 storage -> sane exponent fields; fp32 storage -> random mantissa u16s.
__device__ __forceinline__ int probe_local(const u16* __restrict__ w1, int tid) {
    __shared__ int cnt;
    if (tid == 0) cnt = 0;
    __syncthreads();
    if (tid < 256) {
        u16 u = w1[tid];
        int e = (u >> 7) & 0xFF;
        if ((u == 0) || (e >= 0x60 && e <= 0x8F)) atomicAdd(&cnt, 1);
    }
    __syncthreads();
    return (cnt >= 240) ? 1 : 0;   // 1 = bf16 inputs
}

// R17: 1 element/thread pack; coalesced u16 stores; bit-identical wh layout.
template<int KT, int N>
__device__ __forceinline__ void pack_one(const void* __restrict__ Wraw,
                                         u16* __restrict__ hi, int e, int bf) {
    int f = e >> 3, j = e & 7;
    int lane = f & 63, tile = f >> 6;
    int kt = tile % KT, nt = tile / KT;
    int k = kt * 32 + ((lane >> 4) << 3) + j;
    int n = nt * 16 + (lane & 15);
    float wv = bf ? bf2f(((const u16*)Wraw)[(size_t)k * N + n])
                  : ((const float*)Wraw)[(size_t)k * N + n];
    hi[e] = f2bf(wv);
}

__global__ void pack_all(const void* __restrict__ W1, const void* __restrict__ W2,
                         const void* __restrict__ W3, u16* __restrict__ wh,
                         int* __restrict__ flagp) {
    int bf = probe_local((const u16*)W1, threadIdx.x);
    int g = blockIdx.x * 256 + threadIdx.x;
    if (g == 0) *flagp = bf;
    if (g < W2_OFF)
        pack_one<12, 512>(W1, wh + W1_OFF, g - W1_OFF, bf);
    else if (g < W3_OFF)
        pack_one<16, 512>(W2, wh + W2_OFF, g - W2_OFF, bf);
    else
        pack_one<16, 256>(W3, wh + W3_OFF, g - W3_OFF, bf);
}

#define MFMA __builtin_amdgcn_mfma_f32_16x16x32_bf16

// R18: G = W3 @ W1[0:256,:] computed on-device (bf16 MFMA, fp32 acc, RNE to
// bf16) and stored in the SAME packed B-frag layout as W2p. One wave per
// 32x32 G-tile; A/B loaded straight from raw W3/W1 (L2-hot, tiny kernel).
// A-frag lane map (16-dim=lane&15, k=quad*8+j) verified by the main kernel's
// passing A-reads; store mapping is pack_one's inverse (k=i, n=j).
__global__ void pack_G(const void* __restrict__ W3raw, const void* __restrict__ W1raw,
                       u16* __restrict__ wh, const int* __restrict__ flagp) {
    const int bf = *flagp;
    const int lane = threadIdx.x;          // 64 threads = 1 wave
    const int col16 = lane & 15, quad = lane >> 4;
    const int bi = blockIdx.x & 15;        // G-row (k) tile: rows bi*32..+31
    const int bj = blockIdx.x >> 4;        // G-col (n) tile: cols bj*32..+31
    float4v acc[2][2];
#pragma unroll
    for (int m = 0; m < 2; ++m)
#pragma unroll
        for (int t = 0; t < 2; ++t) acc[m][t] = (float4v){0.f, 0.f, 0.f, 0.f};
#pragma unroll 2
    for (int kt = 0; kt < 8; ++kt) {       // K = 256
        const int k0 = kt * 32 + quad * 8;
        short8 A0, A1, B0, B1;
#pragma unroll
        for (int j = 0; j < 8; ++j) {
            const int kk = k0 + j;
            const int ra0 = bi * 32 + col16, ra1 = ra0 + 16;
            const int cb0 = bj * 32 + col16, cb1 = cb0 + 16;
            float a0, a1, b0, b1;
            if (bf) {
                a0 = bf2f(((const u16*)W3raw)[(size_t)ra0 * 256 + kk]);
                a1 = bf2f(((const u16*)W3raw)[(size_t)ra1 * 256 + kk]);
                b0 = bf2f(((const u16*)W1raw)[(size_t)kk * 512 + cb0]);
                b1 = bf2f(((const u16*)W1raw)[(size_t)kk * 512 + cb1]);
            } else {
                a0 = ((const float*)W3raw)[(size_t)ra0 * 256 + kk];
                a1 = ((const float*)W3raw)[(size_t)ra1 * 256 + kk];
                b0 = ((const float*)W1raw)[(size_t)kk * 512 + cb0];
                b1 = ((const float*)W1raw)[(size_t)kk * 512 + cb1];
            }
            A0[j] = (short)f2bf(a0); A1[j] = (short)f2bf(a1);
            B0[j] = (short)f2bf(b0); B1[j] = (short)f2bf(b1);
        }
        acc[0][0] = MFMA(A0, B0, acc[0][0], 0, 0, 0);
        acc[0][1] = MFMA(A0, B1, acc[0][1], 0, 0, 0);
        acc[1][0] = MFMA(A1, B0, acc[1][0], 0, 0, 0);
        acc[1][1] = MFMA(A1, B1, acc[1][1], 0, 0, 0);
    }
    // acc[m][t][r] = G[i][j], i = bi*32+m*16+quad*4+r (C row), j = bj*32+t*16+col16.
    // Frag store: tile = nt*16+kt' (kt'=i>>5=bi, nt=j>>4=bj*2+t),
    // lane' = (j&15) + 16*((i>>3)&3) = col16 + 16*(m*2+(quad>>1)), elem = i&7.
    // i&7 = (quad&1)*4 + r -> r consecutive -> one 8B store per (m,t).
#pragma unroll
    for (int m = 0; m < 2; ++m)
#pragma unroll
        for (int t = 0; t < 2; ++t) {
            short4v pv;
#pragma unroll
            for (int r = 0; r < 4; ++r) pv[r] = (short)f2bf(acc[m][t][r]);
            const int ntp = bj * 2 + t;
            const int lanep = col16 + 16 * (m * 2 + (quad >> 1));
            u16* dst = wh + G_OFF + ((size_t)(ntp * 16 + bi)) * 512 + lanep * 8 + (quad & 1) * 4;
            *reinterpret_cast<short4v*>(dst) = pv;
        }
}

// c3[j] = sum_k b3[k] * W1[k][j], k<256 — the bias term of the z-recurrence.
__global__ void pack_c3(const void* __restrict__ b3r, const void* __restrict__ W1raw,
                        float* __restrict__ c3, const int* __restrict__ flagp) {
    const int bf = *flagp;
    const int j = blockIdx.x * 128 + threadIdx.x;   // 4 blocks x 128 = 512
    float s = 0.f;
#pragma unroll 4
    for (int k = 0; k < 256; ++k) {
        float b = bf ? bf2f(((const u16*)b3r)[k]) : ((const float*)b3r)[k];
        float wv = bf ? bf2f(((const u16*)W1raw)[(size_t)k * 512 + j])
                      : ((const float*)W1raw)[(size_t)k * 512 + j];
        s += b * wv;
    }
    c3[j] = s;
}

// Compiler-scheduled layer GEMM. unroll 2 ONLY. Register ledger: 1024-thread
// blocks force 4 waves/EU -> 128-reg cap; R14 (+48) and R16 (+40) both
// spilled to scratch (WRITE_SIZE 43-47 MB). Keep added state <= ~24 regs.
template<int KT0, int KT, int KTB, int KTL, int NT>
__device__ __forceinline__ void mm1(const u16* ah, const u16* al, const int as, const int als,
                                    const u16* __restrict__ wh, float4v acc[2][NT]) {
#pragma unroll 2
    for (int kt = KT0; kt < KT; ++kt) {
        short8 A0 = *(const short8*)(ah + kt * 32);
        short8 A1 = *(const short8*)(ah + 16 * as + kt * 32);
        short8 A0l, A1l;
        if (kt < KTL) {
            A0l = *(const short8*)(al + kt * 32);
            A1l = *(const short8*)(al + 16 * als + kt * 32);
        }
#pragma unroll
        for (int t = 0; t < NT; ++t) {
            short8 Bh = *(const short8*)(wh + (size_t)(t * KTB + kt) * 512);
            acc[0][t] = MFMA(A0, Bh, acc[0][t], 0, 0, 0);
            acc[1][t] = MFMA(A1, Bh, acc[1][t], 0, 0, 0);
            if (kt < KTL) {     // x-lo correction reuses Bh — no extra load
                acc[0][t] = MFMA(A0l, Bh, acc[0][t], 0, 0, 0);
                acc[1][t] = MFMA(A1l, Bh, acc[1][t], 0, 0, 0);
            }
        }
    }
}

// R18 phase-A GEMM: facc = H2@W3 (NT=1) and gacc = H2@G (NT=2) SHARING the
// A-frag loads (the whole point: one A-read feeds 6 MFMAs).
__device__ __forceinline__ void mmA(const u16* ah, const int as,
                                    const u16* __restrict__ w3, const u16* __restrict__ g,
                                    float4v facc[2][1], float4v gacc[2][2]) {
#pragma unroll 2
    for (int kt = 0; kt < 16; ++kt) {
        short8 A0 = *(const short8*)(ah + kt * 32);
        short8 A1 = *(const short8*)(ah + 16 * as + kt * 32);
        short8 Bw = *(const short8*)(w3 + (size_t)kt * 512);
        facc[0][0] = MFMA(A0, Bw, facc[0][0], 0, 0, 0);
        facc[1][0] = MFMA(A1, Bw, facc[1][0], 0, 0, 0);
#pragma unroll
        for (int t = 0; t < 2; ++t) {
            short8 Bg = *(const short8*)(g + (size_t)(t * 16 + kt) * 512);
            gacc[0][t] = MFMA(A0, Bg, gacc[0][t], 0, 0, 0);
            gacc[1][t] = MFMA(A1, Bg, gacc[1][t], 0, 0, 0);
        }
    }
}

__device__ __forceinline__ float silu(float v) {
    // v_rcp_f32 rel err ~2^-22, far below the bf16 rounding applied after.
    return v * __builtin_amdgcn_rcpf(1.0f + __expf(-v));
}

// R18 structure: z-recurrence. z_s = x_s@W1[0:256] kept in 16 fp32 regs;
// z' = z + dt*(H2@G + c3) (exact linear-algebra identity), H1 = silu(z+uacc).
// x never exists in the step loop -> L1's GEMM + x LDS round-trip + one of
// three barriers all die. 2 barriers/step, LDS reads -20%, MFMA +25% (G is
// K=512) — MFMA pipe was only 30% busy. Mid-step numerics IMPROVE (old path
// rounded x to bf16-hi each step; z stays fp32; new G-rounding is 2^-8).
template<bool BF>
__device__ __forceinline__ void body(
    const void* state_raw, const void* user_raw,
    const void* b1r, const void* b2r, const void* b3r,
    const u16* __restrict__ wh_all, const float* __restrict__ c3p, void* outp,
    u16* xh, u16* xl, u16* H1, u16* H2) {

    const int tid = threadIdx.x, w = tid >> 6, lane = tid & 63;   // 16 waves
    const int col16 = lane & 15, quad = lane >> 4;
    const int r0 = blockIdx.x * MT;

    // ---- one-time: user params -> xh cols 256..383 (hi only) ----
    if (tid < 512) {
        int row = tid >> 4;
        int c8 = (tid & 15) * 8;
        if (BF) {
            short8 v = *(const short8*)((const u16*)user_raw + (size_t)(r0 + row) * Udim + c8);
            *(short8*)(xh + row * XS + Sdim + c8) = v;
        } else {
            const float* up = (const float*)user_raw + (size_t)(r0 + row) * Udim + c8;
            short8 v;
#pragma unroll
            for (int j = 0; j < 8; ++j) v[j] = (short)f2bf(up[j]);
            *(short8*)(xh + row * XS + Sdim + c8) = v;
        }
    }
    // ---- biases (C-layout: depend on col only) + c3 slice ----
    float b1f[2], b2f[2], b3f, c3f[2];
#pragma unroll
    for (int t = 0; t < 2; ++t) {
        int i = w * 32 + t * 16 + col16;
        b1f[t] = BF ? bf2f(((const u16*)b1r)[i]) : ((const float*)b1r)[i];
        b2f[t] = BF ? bf2f(((const u16*)b2r)[i]) : ((const float*)b2r)[i];
        c3f[t] = c3p[i];
    }
    {
        int i = w * 16 + col16;
        b3f = BF ? bf2f(((const u16*)b3r)[i]) : ((const float*)b3r)[i];
    }
    // ---- state: fp32 regs + hi/lo split into LDS (PROLOGUE-ONLY now) ----
    float st[2][4];
#pragma unroll
    for (int m = 0; m < 2; ++m)
#pragma unroll
        for (int r = 0; r < 4; ++r) {
            int row = m * 16 + quad * 4 + r;
            int col = w * 16 + col16;
            float v = BF ? bf2f(((const u16*)state_raw)[(size_t)(r0 + row) * Sdim + col])
                         : ((const float*)state_raw)[(size_t)(r0 + row) * Sdim + col];
            st[m][r] = v;
            u16 h = f2bf(v);
            xh[row * XS + col] = h;
            xl[row * XLS + col] = f2bf(v - bf2f(h));
        }
    __syncthreads();

    const u16* w1h = wh_all + W1_OFF + (size_t)(w * 2) * 12 * 512 + lane * 8;
    const u16* w2h = wh_all + W2_OFF + (size_t)(w * 2) * 16 * 512 + lane * 8;
    const u16* w3h = wh_all + W3_OFF + (size_t)(w)     * 16 * 512 + lane * 8;
    const u16* gh  = wh_all + G_OFF  + (size_t)(w * 2) * 16 * 512 + lane * 8;

    const u16* aXh = xh + col16 * XS + quad * 8;
    const u16* aXl = xl + col16 * XLS + quad * 8;
    const u16* aH1 = H1 + col16 * HS + quad * 8;
    const u16* aH2 = H2 + col16 * HS + quad * 8;

    // ---- step-invariant: uacc = b1 + user@W1[256:384] (kt 8..11) ----
    float4v uacc[2][2];
#pragma unroll
    for (int m = 0; m < 2; ++m)
#pragma unroll
        for (int t = 0; t < 2; ++t) uacc[m][t] = (float4v){b1f[t], b1f[t], b1f[t], b1f[t]};
    mm1<8, 12, 12, 0, 2>(aXh, aXh, XS, XS, w1h, uacc);

    // ---- z_0 = x_0 @ W1[0:256] at full hi+lo fidelity (once) ----
    float4v z[2][2];
#pragma unroll
    for (int m = 0; m < 2; ++m)
#pragma unroll
        for (int t = 0; t < 2; ++t) z[m][t] = (float4v){0.f, 0.f, 0.f, 0.f};
    mm1<0, 8, 12, 8, 2>(aXh, aXl, XS, XLS, w1h, z);

    // ---- H1_0 = silu(z_0 + uacc) ----
#pragma unroll
    for (int m = 0; m < 2; ++m)
#pragma unroll
        for (int t = 0; t < 2; ++t)
#pragma unroll
            for (int r = 0; r < 4; ++r)
                H1[(m * 16 + quad * 4 + r) * HS + w * 32 + t * 16 + col16] =
                    f2bf(silu(z[m][t][r] + uacc[m][t][r]));
    __syncthreads();

    for (int s = 0; s < NSTEPS; ++s) {
        // ---- phase B: H2 = silu(H1 @ W2 + b2) ----
        {
            float4v acc[2][2];
#pragma unroll
            for (int m = 0; m < 2; ++m)
#pragma unroll
                for (int t = 0; t < 2; ++t) acc[m][t] = (float4v){b2f[t], b2f[t], b2f[t], b2f[t]};
            mm1<0, 16, 16, 0, 2>(aH1, aH1, HS, HS, w2h, acc);
#pragma unroll
            for (int m = 0; m < 2; ++m)
#pragma unroll
                for (int t = 0; t < 2; ++t)
#pragma unroll
                    for (int r = 0; r < 4; ++r)
                        H2[(m * 16 + quad * 4 + r) * HS + w * 32 + t * 16 + col16] =
                            f2bf(silu(acc[m][t][r]));
        }
        __syncthreads();   // H2 visible; fences this step's H1 reads

        // ---- phase A ----
        if (s < NSTEPS - 1) {
            float4v facc[2][1], gacc[2][2];
#pragma unroll
            for (int m = 0; m < 2; ++m) {
                facc[m][0] = (float4v){b3f, b3f, b3f, b3f};
#pragma unroll
                for (int t = 0; t < 2; ++t) gacc[m][t] = (float4v){0.f, 0.f, 0.f, 0.f};
            }
            mmA(aH2, HS, w3h, gh, facc, gacc);
            // z' = z + dt*(H2@G + c3); H1' = silu(z' + uacc); st += dt*f
#pragma unroll
            for (int m = 0; m < 2; ++m) {
#pragma unroll
                for (int t = 0; t < 2; ++t)
#pragma unroll
                    for (int r = 0; r < 4; ++r) {
                        float zv = z[m][t][r] + 0.05f * (gacc[m][t][r] + c3f[t]);
                        z[m][t][r] = zv;
                        H1[(m * 16 + quad * 4 + r) * HS + w * 32 + t * 16 + col16] =
                            f2bf(silu(zv + uacc[m][t][r]));
                    }
#pragma unroll
                for (int r = 0; r < 4; ++r) st[m][r] += 0.05f * facc[m][0][r];
            }
        } else {
            // final unscaled step: only f is needed
            float4v facc[2][1];
#pragma unroll
            for (int m = 0; m < 2; ++m) facc[m][0] = (float4v){b3f, b3f, b3f, b3f};
            mm1<0, 16, 16, 0, 1>(aH2, aH2, HS, HS, w3h, facc);
#pragma unroll
            for (int m = 0; m < 2; ++m)
#pragma unroll
                for (int r = 0; r < 4; ++r) st[m][r] += facc[m][0][r];
        }
        __syncthreads();   // H1' visible; fences this step's H2 reads
    }

    // ---- final state -> out ----
#pragma unroll
    for (int m = 0; m < 2; ++m)
#pragma unroll
        for (int r = 0; r < 4; ++r) {
            int row = m * 16 + quad * 4 + r;
            int col = w * 16 + col16;
            if (BF) ((u16*)outp)[(size_t)(r0 + row) * Sdim + col] = f2bf(st[m][r]);
            else    ((float*)outp)[(size_t)(r0 + row) * Sdim + col] = st[m][r];
        }
}

__global__ __launch_bounds__(1024, 4) void fused_ode(
    const void* state_raw, const void* user_raw,
    const void* b1r, const void* b2r, const void* b3r,
    const u16* __restrict__ wh, const float* __restrict__ c3p,
    const int* __restrict__ flagp, void* outp) {

    __shared__ __align__(16) u16 xh[MT * XS];   // 25,088 B (prologue only)
    __shared__ __align__(16) u16 xl[MT * XLS];  // 16,896 B (prologue only)
    __shared__ __align__(16) u16 H1[MT * HS];   // 33,280 B
    __shared__ __align__(16) u16 H2[MT * HS];   // 33,280 B  -> 108,544 B

    if (*flagp)
        body<true >(state_raw, user_raw, b1r, b2r, b3r, wh, c3p, outp, xh, xl, H1, H2);
    else
        body<false>(state_raw, user_raw, b1r, b2r, b3r, wh, c3p, outp, xh, xl, H1, H2);
}

extern "C" void kernel_launch(void* const* d_in, const int* in_sizes, int n_in,
                              void* d_out, int out_size, void* d_ws, size_t ws_size,
                              hipStream_t stream) {
    u16* wh = (u16*)d_ws;
    float* c3 = (float*)(wh + C3_OFF);
    int* flagp = (int*)((char*)d_ws + FLAG_BYTE);

    pack_all<<<NW / 256, 256, 0, stream>>>(d_in[2], d_in[4], d_in[6], wh, flagp);
    pack_G<<<256, 64, 0, stream>>>(d_in[6], d_in[2], wh, flagp);
    pack_c3<<<4, 128, 0, stream>>>(d_in[7], d_in[2], c3, flagp);

    fused_ode<<<8192 / MT, 1024, 0, stream>>>(d_in[0], d_in[1], d_in[3], d_in[5], d_in[7],
                                              wh, c3, flagp, d_out);
}